// Round 7
// baseline (281.281 us; speedup 1.0000x reference)
//
#include <hip/hip_runtime.h>

namespace {
constexpr int B = 16, C = 19, H = 512, W = 512;
constexpr int TPB = 128;               // 2 waves; thread t owns cols 4t..4t+3
constexpr int HC = 32;                 // output rows per block
constexpr int NHC = H / HC;            // 16
constexpr int NXCD = 8;
constexpr int TILES = B * NHC;         // 256 (b,hc) target tiles
constexpr int TPX = TILES / NXCD;      // 32
constexpr int NBLK = TILES * C;        // 4864 = 8*608 (XCD swizzle bijective)
constexpr int REPS = 3;                // DIAGNOSTIC: repeat body so dispatch >190us -> visible in rocprof top-5
constexpr float SCALE = 1.0f / (float)((long long)B * H * W * REPS);
}

// Raw per-row loads: 6 X values (cols colA..colA+3, colB..colB+1) + 6 labels.
struct Raw {
    float xa0, xa1, xa2, xa3, xb0, xb1;
    int   ta0, ta1, ta2, ta3, tb0, tb1;
};
// Separable-Sobel row aggregates for the 4 owned columns:
//   d = x[w+1]-x[w-1]; s = x[w-1]+2x[w]+x[w+1];  e,u same on one-hot mask.
//   gx = d(h-1)+2d(h)+d(h+1); gy = s(h+1)-s(h-1); hx,hy likewise from e,u.
struct Agg { float d0,d1,d2,d3, s0,s1,s2,s3, e0,e1,e2,e3, u0,u1,u2,u3; };

__global__ void zero_out_kernel(float* out) { *out = 0.0f; }

__global__ __launch_bounds__(TPB) void edge_loss_kernel(
    const float* __restrict__ X,   // [B,C,H,W] f32
    const int*   __restrict__ T,   // [B,H,W] int32 labels
    float* __restrict__ out)
{
    // XCD swizzle: bid%8 -> XCD. All 19 class-blocks of one (b,hc) tile go to
    // ONE XCD, adjacent in dispatch order -> T tile L2-resident, fetched once.
    int i = (int)blockIdx.x;
    const int xcd  = i & (NXCD - 1);
    const int j    = i >> 3;
    const int c    = j % C;
    const int tl   = j / C;
    const int tile = xcd * TPX + tl;
    const int b    = tile >> 4;            // / NHC
    const int hc   = tile & (NHC - 1);
    const int h0   = hc * HC;

    const int tid  = (int)threadIdx.x;
    const int w0   = tid << 2;
    const bool imgL = (tid == 0);
    const bool imgR = (tid == TPB - 1);
    const int colA = imgL ? 0 : (w0 - 1);          // 4-wide load base (never OOB)
    const int colB = imgR ? (w0 + 2) : (w0 + 3);   // 2-wide load base (never OOB)

    const float* __restrict__ Xs = X + (size_t)(b * C + c) * (size_t)(H * W);
    const int*   __restrict__ Ts = T + (size_t)b * (size_t)(H * W);

    const int r0 = (hc == 0) ? 0 : (h0 - 1);       // clamped first row
    const int step1 = (hc == 0) ? 0 : W;

    // mutable streaming pointers (reset each rep)
    const float* pxa; const float* pxb;
    const int*   pta; const int*   ptb;

    auto issue = [&](Raw& q) {                     // 4 mergeable loads (x4,x2 ×2)
        q.xa0 = pxa[0]; q.xa1 = pxa[1]; q.xa2 = pxa[2]; q.xa3 = pxa[3];
        q.xb0 = pxb[0]; q.xb1 = pxb[1];
        q.ta0 = pta[0]; q.ta1 = pta[1]; q.ta2 = pta[2]; q.ta3 = pta[3];
        q.tb0 = ptb[0]; q.tb1 = ptb[1];
    };
    auto advance = [&](int dw) { pxa += dw; pxb += dw; pta += dw; ptb += dw; };

    auto aggregate = [&](Agg& g, const Raw& q) {
        // branchless border remap (masks are loop-invariant vcc pairs)
        const float xm = imgL ? 0.f   : q.xa0;
        const float x0 = imgL ? q.xa0 : q.xa1;
        const float x1 = imgL ? q.xa1 : q.xa2;
        const float x2 = imgL ? q.xa2 : q.xa3;
        const float x3 = imgR ? q.xb1 : q.xb0;
        const float xp = imgR ? 0.f   : q.xb1;
        const float nA = (q.ta0 == c) ? 1.f : 0.f;
        const float nB = (q.ta1 == c) ? 1.f : 0.f;
        const float nC = (q.ta2 == c) ? 1.f : 0.f;
        const float nD = (q.ta3 == c) ? 1.f : 0.f;
        const float nE = (q.tb0 == c) ? 1.f : 0.f;
        const float nF = (q.tb1 == c) ? 1.f : 0.f;
        const float mm = imgL ? 0.f : nA;
        const float m0 = imgL ? nA  : nB;
        const float m1 = imgL ? nB  : nC;
        const float m2 = imgL ? nC  : nD;
        const float m3 = imgR ? nF  : nE;
        const float mp = imgR ? 0.f : nF;
        g.d0 = x1 - xm; g.d1 = x2 - x0; g.d2 = x3 - x1; g.d3 = xp - x2;
        g.s0 = fmaf(2.f, x0, xm + x1); g.s1 = fmaf(2.f, x1, x0 + x2);
        g.s2 = fmaf(2.f, x2, x1 + x3); g.s3 = fmaf(2.f, x3, x2 + xp);
        g.e0 = m1 - mm; g.e1 = m2 - m0; g.e2 = m3 - m1; g.e3 = mp - m2;
        g.u0 = fmaf(2.f, m0, mm + m1); g.u1 = fmaf(2.f, m1, m0 + m2);
        g.u2 = fmaf(2.f, m2, m1 + m3); g.u3 = fmaf(2.f, m3, m2 + mp);
    };
    auto zagg = [&](Agg& g) {
        g.d0=g.d1=g.d2=g.d3 = g.s0=g.s1=g.s2=g.s3 =
        g.e0=g.e1=g.e2=g.e3 = g.u0=g.u1=g.u2=g.u3 = 0.f;
    };

    float ac0 = 0.f, ac1 = 0.f, ac2 = 0.f, ac3 = 0.f;
    auto comp = [&](const Agg& A, const Agg& Bb, const Agg& Cc) {
#define CM(k) {                                                     \
        const float gx = fmaf(2.f, Bb.d##k, A.d##k + Cc.d##k);      \
        const float gy = Cc.s##k - A.s##k;                          \
        const float hx = fmaf(2.f, Bb.e##k, A.e##k + Cc.e##k);      \
        const float hy = Cc.u##k - A.u##k;                          \
        const float dd = (fabsf(gx) + fabsf(gy))                    \
                       - (fabsf(hx) + fabsf(hy));                   \
        ac##k = fmaf(dd, dd, ac##k); }
        CM(0) CM(1) CM(2) CM(3)
#undef CM
    };

    #pragma unroll 1
    for (int rep = 0; rep < REPS; ++rep) {
        // reset streaming pointers to clamped first row
        pxa = Xs + (size_t)r0 * W + colA;
        pxb = Xs + (size_t)r0 * W + colB;
        pta = Ts + (size_t)r0 * W + colA;
        ptb = Ts + (size_t)r0 * W + colB;

        Raw qa, qb;
        Agg g0, g1, g2;

        // ---- pipeline prologue ----
        issue(qa);                    // row h0-1 (clamped to row 0 when hc==0)
        advance(step1);
        issue(qb);                    // row h0
        advance(W);
        aggregate(g0, qa);
        if (hc == 0) zagg(g0);        // zero-pad top border (block-uniform)
        issue(qa);                    // row h0+1
        advance(W);
        aggregate(g1, qb);

        // ---- steady state: iter t issues row h0+t+2, aggregates h0+t+1,
        //      combines output row h0+t.  t = 0..29, unroll 6
#define PSTEP(QI, QC, GA, GB, GC) \
        issue(QI); advance(W);    \
        aggregate(GC, QC);        \
        comp(GA, GB, GC);

        for (int t6 = 0; t6 < 5; ++t6) {
            PSTEP(qb, qa, g0, g1, g2)
            PSTEP(qa, qb, g1, g2, g0)
            PSTEP(qb, qa, g2, g0, g1)
            PSTEP(qa, qb, g0, g1, g2)
            PSTEP(qb, qa, g1, g2, g0)
            PSTEP(qa, qb, g2, g0, g1)
        }
#undef PSTEP

        // ---- epilogue ----
        // t=30: issue row h0+32 (clamped for the last chunk), consume qa (row h0+31)
        {
            const int back = (hc == NHC - 1) ? W : 0;
            pxa -= back; pxb -= back; pta -= back; ptb -= back;
            issue(qb);
            aggregate(g2, qa);
            comp(g0, g1, g2);         // output row h0+30
        }
        // t=31: consume qb (row h0+32; zero-pad if below image)
        {
            aggregate(g0, qb);
            if (hc == NHC - 1) zagg(g0);
            comp(g1, g2, g0);         // output row h0+31
        }
    }

    // ---- reduce: fold 4 cols -> wave shuffle -> LDS (2 waves) -> 1 atomic ----
    float a = (ac0 + ac1) + (ac2 + ac3);
    #pragma unroll
    for (int off = 32; off > 0; off >>= 1)
        a += __shfl_down(a, off, 64);

    __shared__ float wsum[TPB / 64];
    const int lane = tid & 63;
    const int wid  = tid >> 6;
    if (lane == 0) wsum[wid] = a;
    __syncthreads();
    if (tid == 0) atomicAdd(out, (wsum[0] + wsum[1]) * SCALE);
}

extern "C" void kernel_launch(void* const* d_in, const int* in_sizes, int n_in,
                              void* d_out, int out_size, void* d_ws, size_t ws_size,
                              hipStream_t stream) {
    (void)in_sizes; (void)n_in; (void)d_ws; (void)ws_size; (void)out_size;
    const float* X = (const float*)d_in[0];
    const int*   T = (const int*)d_in[1];
    float* out = (float*)d_out;

    zero_out_kernel<<<1, 1, 0, stream>>>(out);
    edge_loss_kernel<<<NBLK, TPB, 0, stream>>>(X, T, out);
}

// Round 8
// 129.849 us; speedup vs baseline: 2.1662x; 2.1662x over previous
//
#include <hip/hip_runtime.h>

namespace {
constexpr int B = 16, C = 19, H = 512, W = 512;
constexpr int TPB = 128;               // 2 waves; thread t owns cols 4t..4t+3 (full 512)
constexpr int HC = 32;                 // output rows per block
constexpr int NHC = H / HC;            // 16
constexpr int NXCD = 8;
constexpr int TILES = B * NHC;         // 256 (b,hc) target tiles
constexpr int TPX = TILES / NXCD;      // 32
constexpr int NBLK = TILES * C;        // 4864 = 8*608 (XCD swizzle bijective)
constexpr float SCALE = 1.0f / (float)((long long)B * H * W);
}

// Raw row loads: aligned 4-wide main + 2 clamped halo scalars, X and T planes.
struct Raw { float4 x; float xl, xr; int4 t; int tl, tr; };
// Separable-Sobel row aggregates (4 owned cols): d=x[w+1]-x[w-1];
// s=x[w-1]+2x[w]+x[w+1]; e,u same on the one-hot mask plane.
// gx=d(h-1)+2d(h)+d(h+1); gy=s(h+1)-s(h-1); hx,hy likewise.
struct Agg { float4 d, s, e, u; };

__global__ void zero_out_kernel(float* out) { *out = 0.0f; }

__global__ __launch_bounds__(TPB, 4) void edge_loss_kernel(
    const float* __restrict__ X,   // [B,C,H,W] f32
    const int*   __restrict__ T,   // [B,H,W] int32 labels
    float* __restrict__ out)
{
    // XCD swizzle: bid%8 -> XCD; all 19 class-blocks of one (b,hc) tile are
    // adjacent on ONE XCD -> T tile L2-resident, fetched once per XCD.
    int i = (int)blockIdx.x;
    const int xcd  = i & (NXCD - 1);
    const int j    = i >> 3;
    const int c    = j % C;
    const int tl_  = j / C;
    const int tile = xcd * TPX + tl_;
    const int b    = tile >> 4;            // / NHC
    const int hc   = tile & (NHC - 1);
    const int h0   = hc * HC;

    const int tid = (int)threadIdx.x;
    const int w0  = tid << 2;
    // clamped halo columns + border factors (per-thread constants)
    const int   colL = (w0 > 0)     ? (w0 - 1) : 0;
    const int   colR = (w0 + 4 < W) ? (w0 + 4) : (W - 1);
    const float fl   = (w0 > 0)     ? 1.0f : 0.0f;
    const float fr   = (w0 + 4 < W) ? 1.0f : 0.0f;

    const float* __restrict__ Xs = X + (size_t)(b * C + c) * (size_t)(H * W);
    const int*   __restrict__ Ts = T + (size_t)b * (size_t)(H * W);

    // wave-uniform row bases (SGPR; advanced by SALU adds) + per-thread offsets
    const int r0 = (hc == 0) ? 0 : (h0 - 1);
    const int step1 = (hc == 0) ? 0 : W;
    const float* xb = Xs + (size_t)r0 * W;
    const int*   tb = Ts + (size_t)r0 * W;

    Raw q0, q1, q2;
    Agg ga, gb, gc;
    float ac0 = 0.f, ac1 = 0.f, ac2 = 0.f, ac3 = 0.f;

#define ISSUE(Q)                                                     \
    {                                                                \
        (Q).x  = *reinterpret_cast<const float4*>(xb + w0);          \
        (Q).xl = xb[colL]; (Q).xr = xb[colR];                        \
        (Q).t  = *reinterpret_cast<const int4*>(tb + w0);            \
        (Q).tl = tb[colL]; (Q).tr = tb[colR];                        \
        xb += W; tb += W;                                            \
    }

#define AGG(G, Q)                                                    \
    {                                                                \
        const float xm = (Q).xl * fl;                                \
        const float xp = (Q).xr * fr;                                \
        const float m0 = ((Q).t.x == c) ? 1.f : 0.f;                 \
        const float m1 = ((Q).t.y == c) ? 1.f : 0.f;                 \
        const float m2 = ((Q).t.z == c) ? 1.f : 0.f;                 \
        const float m3 = ((Q).t.w == c) ? 1.f : 0.f;                 \
        const float mm = ((Q).tl  == c) ? fl  : 0.f;                 \
        const float mp = ((Q).tr  == c) ? fr  : 0.f;                 \
        (G).d.x = (Q).x.y - xm;      (G).d.y = (Q).x.z - (Q).x.x;    \
        (G).d.z = (Q).x.w - (Q).x.y; (G).d.w = xp - (Q).x.z;         \
        (G).s.x = fmaf(2.f, (Q).x.x, xm + (Q).x.y);                  \
        (G).s.y = fmaf(2.f, (Q).x.y, (Q).x.x + (Q).x.z);             \
        (G).s.z = fmaf(2.f, (Q).x.z, (Q).x.y + (Q).x.w);             \
        (G).s.w = fmaf(2.f, (Q).x.w, (Q).x.z + xp);                  \
        (G).e.x = m1 - mm; (G).e.y = m2 - m0;                        \
        (G).e.z = m3 - m1; (G).e.w = mp - m2;                        \
        (G).u.x = fmaf(2.f, m0, mm + m1);                            \
        (G).u.y = fmaf(2.f, m1, m0 + m2);                            \
        (G).u.z = fmaf(2.f, m2, m1 + m3);                            \
        (G).u.w = fmaf(2.f, m3, m2 + mp);                            \
    }

#define ZAGG(G)                                                      \
    (G).d = (G).s = (G).e = (G).u = make_float4(0.f, 0.f, 0.f, 0.f);

#define COMP(A, Bb, Cc)                                              \
    {                                                                \
        float gx, gy, hx, hy, dd;                                    \
        gx = fmaf(2.f, (Bb).d.x, (A).d.x + (Cc).d.x);                \
        gy = (Cc).s.x - (A).s.x;                                     \
        hx = fmaf(2.f, (Bb).e.x, (A).e.x + (Cc).e.x);                \
        hy = (Cc).u.x - (A).u.x;                                     \
        dd = (fabsf(gx) + fabsf(gy)) - (fabsf(hx) + fabsf(hy));      \
        ac0 = fmaf(dd, dd, ac0);                                     \
        gx = fmaf(2.f, (Bb).d.y, (A).d.y + (Cc).d.y);                \
        gy = (Cc).s.y - (A).s.y;                                     \
        hx = fmaf(2.f, (Bb).e.y, (A).e.y + (Cc).e.y);                \
        hy = (Cc).u.y - (A).u.y;                                     \
        dd = (fabsf(gx) + fabsf(gy)) - (fabsf(hx) + fabsf(hy));      \
        ac1 = fmaf(dd, dd, ac1);                                     \
        gx = fmaf(2.f, (Bb).d.z, (A).d.z + (Cc).d.z);                \
        gy = (Cc).s.z - (A).s.z;                                     \
        hx = fmaf(2.f, (Bb).e.z, (A).e.z + (Cc).e.z);                \
        hy = (Cc).u.z - (A).u.z;                                     \
        dd = (fabsf(gx) + fabsf(gy)) - (fabsf(hx) + fabsf(hy));      \
        ac2 = fmaf(dd, dd, ac2);                                     \
        gx = fmaf(2.f, (Bb).d.w, (A).d.w + (Cc).d.w);                \
        gy = (Cc).s.w - (A).s.w;                                     \
        hx = fmaf(2.f, (Bb).e.w, (A).e.w + (Cc).e.w);                \
        hy = (Cc).u.w - (A).u.w;                                     \
        dd = (fabsf(gx) + fabsf(gy)) - (fabsf(hx) + fabsf(hy));      \
        ac3 = fmaf(dd, dd, ac3);                                     \
    }

    // ---- prologue: issue rows h0-1, h0, h0+1 (distance-2 pipeline fill) ----
    // first advance is step1 (0 when hc==0 so row h0 re-reads row 0; its
    // aggregate ga is zeroed below, value irrelevant, address in-bounds)
    {
        ISSUE(q0);                 // row h0-1 (clamped)
        xb += (step1 - W); tb += (step1 - W);   // net advance = step1
        ISSUE(q1);                 // row h0
        ISSUE(q2);                 // row h0+1
    }
    AGG(ga, q0);
    if (hc == 0) { ZAGG(ga); }
    // S1: issue row h0+2, aggregate row h0
    ISSUE(q0);
    AGG(gb, q1);

    // ---- steady state: iter k issues row h0+3+k, aggregates row h0+1+k
    //      (issued 2 iters earlier), outputs row h0+k.  k = 0..28 ----
    for (int t3 = 0; t3 < 9; ++t3) {           // k = 0..26
        ISSUE(q1); AGG(gc, q2); COMP(ga, gb, gc);
        ISSUE(q2); AGG(ga, q0); COMP(gb, gc, ga);
        ISSUE(q0); AGG(gb, q1); COMP(gc, ga, gb);
    }
    ISSUE(q1); AGG(gc, q2); COMP(ga, gb, gc);  // k = 27
    ISSUE(q2); AGG(ga, q0); COMP(gb, gc, ga);  // k = 28

    // ---- epilogue ----
    // E0 (k=29): issue row h0+32 (clamped back one row for the last chunk),
    //            aggregate row h0+30, output row h0+29
    {
        const int back = (hc == NHC - 1) ? W : 0;
        xb -= back; tb -= back;
        ISSUE(q0);
        AGG(gb, q1); COMP(gc, ga, gb);
    }
    // E1 (k=30): aggregate row h0+31, output row h0+30
    AGG(gc, q2); COMP(ga, gb, gc);
    // E2 (k=31): aggregate row h0+32 (zero-pad if last chunk), output h0+31
    AGG(ga, q0);
    if (hc == NHC - 1) { ZAGG(ga); }
    COMP(gb, gc, ga);

#undef ISSUE
#undef AGG
#undef ZAGG
#undef COMP

    // ---- reduce: fold 4 cols -> wave shuffle -> LDS (2 waves) -> 1 atomic ----
    float a = (ac0 + ac1) + (ac2 + ac3);
    #pragma unroll
    for (int off = 32; off > 0; off >>= 1)
        a += __shfl_down(a, off, 64);

    __shared__ float wsum[TPB / 64];
    const int lane = tid & 63;
    const int wid  = tid >> 6;
    if (lane == 0) wsum[wid] = a;
    __syncthreads();
    if (tid == 0) atomicAdd(out, (wsum[0] + wsum[1]) * SCALE);
}

extern "C" void kernel_launch(void* const* d_in, const int* in_sizes, int n_in,
                              void* d_out, int out_size, void* d_ws, size_t ws_size,
                              hipStream_t stream) {
    (void)in_sizes; (void)n_in; (void)d_ws; (void)ws_size; (void)out_size;
    const float* X = (const float*)d_in[0];
    const int*   T = (const int*)d_in[1];
    float* out = (float*)d_out;

    zero_out_kernel<<<1, 1, 0, stream>>>(out);
    edge_loss_kernel<<<NBLK, TPB, 0, stream>>>(X, T, out);
}